// Round 2
// baseline (866.671 us; speedup 1.0000x reference)
//
#include <hip/hip_runtime.h>
#include <math.h>

typedef float f4 __attribute__((ext_vector_type(4)));

#define D    2048
#define NE   64
#define TB   64          // tokens per block
#define KCH  32          // k per LDS chunk

// ---------------- kernel 1: K-split GEMM partials ----------------
// One wave (64 threads) per block. Wave computes a full 64-token x 64-expert
// tile over its K-range. Lane (lr,lc) = (l&7, l>>3) owns tokens lr+8i,
// experts lc*8+j (i,j in 0..7) -> acc[8][8].
// x: staged in LDS (double-buffered, XOR-swizzled granules, read 0.5 B/fma).
// W: loaded straight from global (L2-resident) into registers, 2-deep rotate.
// No barriers needed: single-wave block, compiler waitcnts handle LDS deps.
__global__ __launch_bounds__(64, 2)
void moe_gemm_part(const float* __restrict__ x,
                   const float* __restrict__ W,
                   float* __restrict__ ws,
                   int ntok, int krange)
{
    __shared__ float Xs[2][TB * KCH];      // 2 x 8 KB

    const int mbc = ntok >> 6;             // 256 m-blocks
    const int mb  = blockIdx.x % mbc;
    const int ks  = blockIdx.x / mbc;
    const int k0  = ks * krange;
    const int nch = krange / KCH;

    const int l  = threadIdx.x;
    const int lr = l & 7;                  // token sub-row
    const int lc = l >> 3;                 // expert group (8 experts each)
    const int tok0 = mb * TB;

    // staging geometry: granule g = p*64 + l ; row = g>>3 (token), c = g&7
    const int srow = l >> 3;               // rows srow, srow+8*? per p handled below
    const int sc   = l & 7;

    float acc[8][8] = {};
    f4 xr[8];                              // global->reg staging for next chunk
    f4 wreg[2][8];                         // W window double-buffer (static idx)

    // ---- prologue: stage chunk 0 into LDS buffer 0 ----
#pragma unroll
    for (int p = 0; p < 8; ++p) {
        const int row = p * 8 + srow;
        xr[p] = *(const f4*)(x + (size_t)(tok0 + row) * D + k0 + sc * 4);
    }
#pragma unroll
    for (int p = 0; p < 8; ++p) {
        const int row = p * 8 + srow;
        Xs[0][row * KCH + (((sc ^ row) & 7) << 2) + 0] = xr[p].x;
        *(f4*)&Xs[0][row * KCH + (((sc ^ row) & 7) << 2)] = xr[p];
    }

    // ---- prologue: W window 0 ----
#pragma unroll
    for (int j = 0; j < 8; ++j)
        wreg[0][j] = *(const f4*)(W + (size_t)(lc * 8 + j) * D + k0);

    for (int ch = 0; ch < nch; ++ch) {
        // issue next x chunk's global loads early (hidden under this chunk)
        if (ch + 1 < nch) {
#pragma unroll
            for (int p = 0; p < 8; ++p) {
                const int row = p * 8 + srow;
                xr[p] = *(const f4*)(x + (size_t)(tok0 + row) * D
                                     + k0 + (ch + 1) * KCH + sc * 4);
            }
        }

        const float* Xb = &Xs[ch & 1][0];

#pragma unroll
        for (int w = 0; w < 8; ++w) {      // 8 k4-windows per chunk
            const int pcur = w & 1;
            const int pnxt = pcur ^ 1;

            // prefetch next W window (guard last window -> harmless reload)
            {
                int kkn = k0 + (ch * 8 + w + 1) * 4;
                if (ch == nch - 1 && w == 7) kkn = k0;
                const float* wp = W + kkn;
#pragma unroll
                for (int j = 0; j < 8; ++j)
                    wreg[pnxt][j] = *(const f4*)(wp + (size_t)(lc * 8 + j) * D);
            }

            // x fragment: 8 swizzled b128 reads, conflict-free
            f4 xv[8];
#pragma unroll
            for (int i = 0; i < 8; ++i) {
                const int row = lr + 8 * i;          // row&7 == lr
                xv[i] = *(const f4*)&Xb[row * KCH + (((w ^ lr) & 7) << 2)];
            }

            // 256 fmaf
#pragma unroll
            for (int i = 0; i < 8; ++i)
#pragma unroll
                for (int j = 0; j < 8; ++j) {
                    float s = acc[i][j];
                    s = fmaf(xv[i].x, wreg[pcur][j].x, s);
                    s = fmaf(xv[i].y, wreg[pcur][j].y, s);
                    s = fmaf(xv[i].z, wreg[pcur][j].z, s);
                    s = fmaf(xv[i].w, wreg[pcur][j].w, s);
                    acc[i][j] = s;
                }
        }

        // write next chunk into the other LDS buffer
        if (ch + 1 < nch) {
            float* Xn = &Xs[(ch + 1) & 1][0];
#pragma unroll
            for (int p = 0; p < 8; ++p) {
                const int row = p * 8 + srow;
                *(f4*)&Xn[row * KCH + (((sc ^ row) & 7) << 2)] = xr[p];
            }
        }
    }

    // ---- store partials: ws[ks][tok][e], coalesced 32B per lane-token ----
    float* wp = ws + ((size_t)ks * ntok + tok0) * NE;
#pragma unroll
    for (int i = 0; i < 8; ++i) {
        const size_t off = (size_t)(lr + 8 * i) * NE + lc * 8;
        f4 v0 = { acc[i][0], acc[i][1], acc[i][2], acc[i][3] };
        f4 v1 = { acc[i][4], acc[i][5], acc[i][6], acc[i][7] };
        *(f4*)(wp + off)     = v0;
        *(f4*)(wp + off + 4) = v1;
    }
}

// ---------------- kernel 2: reduce K-splits + top-2 + softmax ----------------
__global__ __launch_bounds__(64)
void moe_top2(const float* __restrict__ ws,
              float* __restrict__ out,
              int ntok, int nks)
{
    const int tok = blockIdx.x * 64 + threadIdx.x;

    float lg[NE];
    const float* p0 = ws + (size_t)tok * NE;
#pragma unroll
    for (int g = 0; g < 16; ++g) {
        f4 v = *(const f4*)(p0 + g * 4);
        lg[4 * g + 0] = v.x; lg[4 * g + 1] = v.y;
        lg[4 * g + 2] = v.z; lg[4 * g + 3] = v.w;
    }
    for (int ks = 1; ks < nks; ++ks) {
        const float* pk = ws + ((size_t)ks * ntok + tok) * NE;
#pragma unroll
        for (int g = 0; g < 16; ++g) {
            f4 v = *(const f4*)(pk + g * 4);
            lg[4 * g + 0] += v.x; lg[4 * g + 1] += v.y;
            lg[4 * g + 2] += v.z; lg[4 * g + 3] += v.w;
        }
    }

    float m1 = -INFINITY, m2 = -INFINITY;
    int i1 = 0, i2 = 0;
#pragma unroll
    for (int e = 0; e < NE; ++e) {
        float v = lg[e];
        // strict > keeps lowest index on ties, matching jax.lax.top_k
        if (v > m1)      { m2 = m1; i2 = i1; m1 = v; i1 = e; }
        else if (v > m2) { m2 = v;  i2 = e; }
    }
    const float p1 = 1.0f / (1.0f + expf(m2 - m1));   // stable: m2 <= m1
    const float p2 = 1.0f - p1;

    out[(size_t)tok * 2 + 0] = (float)i1;
    out[(size_t)tok * 2 + 1] = (float)i2;
    float* vals = out + (size_t)ntok * 2;
    vals[(size_t)tok * 2 + 0] = p1;
    vals[(size_t)tok * 2 + 1] = p2;
}

extern "C" void kernel_launch(void* const* d_in, const int* in_sizes, int n_in,
                              void* d_out, int out_size, void* d_ws, size_t ws_size,
                              hipStream_t stream)
{
    const float* x = (const float*)d_in[0];
    const float* W = (const float*)d_in[1];
    float* out = (float*)d_out;
    float* ws  = (float*)d_ws;

    const int ntok = in_sizes[0] / D;                 // 16384
    int KS = 8;                                       // K-split factor
    while (KS > 1 && (size_t)KS * ntok * NE * 4 > ws_size) KS >>= 1;
    const int krange = D / KS;

    moe_gemm_part<<<dim3((ntok / TB) * KS), 64, 0, stream>>>(x, W, ws, ntok, krange);
    moe_top2<<<dim3(ntok / 64), 64, 0, stream>>>(ws, out, ntok, KS);
}

// Round 3
// 226.112 us; speedup vs baseline: 3.8329x; 3.8329x over previous
//
#include <hip/hip_runtime.h>
#include <math.h>

typedef float f4 __attribute__((ext_vector_type(4)));

#define D     2048
#define NE    64
#define TPB   256            // threads per block (k1) = tokens per block
#define KCH   32             // k per LDS chunk
#define WT4N  (D * NE)       // floats in transposed W

#define AS1C(p) ((const __attribute__((address_space(1))) void*)(p))
#define AS3(p)  ((__attribute__((address_space(3))) void*)(p))

// ---------------- kernel 0: W[e][k] -> Wt4[k>>2][e][k&3] ----------------
__global__ __launch_bounds__(256)
void wtrans(const float* __restrict__ W, float* __restrict__ Wt4)
{
    const int i = blockIdx.x * 256 + threadIdx.x;   // 131072 total
    const int e = i >> 11;                          // coalesced read along k
    const int k = i & 2047;
    Wt4[(size_t)(k >> 2) * (NE * 4) + e * 4 + (k & 3)] = W[i];
}

// ---------------- kernel 1: K-split logit partials ----------------
// Thread t owns token tok0+t and ALL 64 experts: acc[64].
// W fed from SGPRs (uniform s_load of Wt4) -> ~97% of VALU stream is v_fmac.
// x staged to LDS via global_load_lds (zero VGPR), src-side XOR swizzle,
// double-buffered with counted vmcnt (gload_lds is the only vmem in loop).
__global__ __launch_bounds__(TPB)
void moe_gemm_part(const float* __restrict__ x,
                   const float* __restrict__ Wt4,
                   float* __restrict__ part,
                   int ntok, int ks_count)
{
    __shared__ float Xs[2][TPB * KCH];              // 2 x 32 KB

    const int t    = threadIdx.x;
    const int wv   = t >> 6;                        // wave id (0..3)
    const int l    = t & 63;
    const int mbc  = ntok >> 8;                     // 64 m-blocks
    const int mb   = blockIdx.x % mbc;
    const int ks   = blockIdx.x / mbc;
    const int krange = D / ks_count;
    const int nch  = krange / KCH;
    const int k0   = ks * krange;
    const int tok0 = mb * TPB;

    // gload_lds geometry: lane l -> row r=l>>3 within an 8-row group, slot l&7.
    // Source col pre-swizzled so LDS[r][s] holds logical col s^(r&7) (rule 21).
    const int lr8  = l >> 3;
    const int scol = ((l & 7) ^ lr8) << 2;          // floats
    const float* xsrc = x + (size_t)(tok0 + wv * 64 + lr8) * D + k0 + scol;

    float acc[NE] = {};

#define STAGE(buf, ch)                                                        \
    {                                                                         \
        const float* gp_ = xsrc + (size_t)(ch) * KCH;                         \
        _Pragma("unroll")                                                     \
        for (int p = 0; p < 8; ++p)                                           \
            __builtin_amdgcn_global_load_lds(                                 \
                AS1C(gp_ + (size_t)p * 8 * D),                                \
                AS3(&Xs[buf][(wv * 64 + p * 8) * KCH]), 16, 0, 0);            \
    }

#define COMPUTE(buf, ch)                                                      \
    {                                                                         \
        const float* wchb_ = Wt4 + ((size_t)(k0 + (ch) * KCH) >> 2) * 256;    \
        _Pragma("unroll")                                                     \
        for (int w = 0; w < KCH / 4; ++w) {                                   \
            const f4 xv = *(const f4*)&Xs[buf][t * KCH + ((w ^ (t & 7)) << 2)];\
            const float* wb_ = wchb_ + w * 256;                               \
            _Pragma("unroll")                                                 \
            for (int eg = 0; eg < 16; ++eg) {                                 \
                const f4 w0 = *(const f4*)(wb_ + eg * 16 + 0);                \
                const f4 w1 = *(const f4*)(wb_ + eg * 16 + 4);                \
                const f4 w2 = *(const f4*)(wb_ + eg * 16 + 8);                \
                const f4 w3 = *(const f4*)(wb_ + eg * 16 + 12);               \
                float a0 = acc[4 * eg + 0], a1 = acc[4 * eg + 1];             \
                float a2 = acc[4 * eg + 2], a3 = acc[4 * eg + 3];             \
                a0 = fmaf(xv.x, w0.x, a0); a0 = fmaf(xv.y, w0.y, a0);         \
                a0 = fmaf(xv.z, w0.z, a0); a0 = fmaf(xv.w, w0.w, a0);         \
                a1 = fmaf(xv.x, w1.x, a1); a1 = fmaf(xv.y, w1.y, a1);         \
                a1 = fmaf(xv.z, w1.z, a1); a1 = fmaf(xv.w, w1.w, a1);         \
                a2 = fmaf(xv.x, w2.x, a2); a2 = fmaf(xv.y, w2.y, a2);         \
                a2 = fmaf(xv.z, w2.z, a2); a2 = fmaf(xv.w, w2.w, a2);         \
                a3 = fmaf(xv.x, w3.x, a3); a3 = fmaf(xv.y, w3.y, a3);         \
                a3 = fmaf(xv.z, w3.z, a3); a3 = fmaf(xv.w, w3.w, a3);         \
                acc[4 * eg + 0] = a0; acc[4 * eg + 1] = a1;                   \
                acc[4 * eg + 2] = a2; acc[4 * eg + 3] = a3;                   \
            }                                                                 \
        }                                                                     \
    }

    // prologue
    STAGE(0, 0);

    for (int ch = 0; ch < nch - 1; ++ch) {
        __builtin_amdgcn_sched_barrier(0);   // pin: prev ds_reads stay before next stage
        STAGE((ch + 1) & 1, ch + 1);
        // wait for the OLDER 8 loads (prev chunk); keep 8 newer in flight (T4)
        asm volatile("s_waitcnt vmcnt(8)" ::: "memory");
        if (ch & 1) { COMPUTE(1, ch); } else { COMPUTE(0, ch); }
    }
    asm volatile("s_waitcnt vmcnt(0)" ::: "memory");
    if ((nch - 1) & 1) { COMPUTE(1, nch - 1); } else { COMPUTE(0, nch - 1); }

#undef STAGE
#undef COMPUTE

    // store partials: part[ks][token][e]
    float* pp = part + ((size_t)ks * ntok + tok0 + t) * NE;
#pragma unroll
    for (int eg = 0; eg < 16; ++eg) {
        f4 v = { acc[4 * eg + 0], acc[4 * eg + 1],
                 acc[4 * eg + 2], acc[4 * eg + 3] };
        *(f4*)(pp + eg * 4) = v;
    }
}

// ---------------- kernel 2: reduce K-splits + top-2 + softmax ----------------
__global__ __launch_bounds__(64)
void moe_top2(const float* __restrict__ part,
              float* __restrict__ out,
              int ntok, int nks)
{
    const int tok = blockIdx.x * 64 + threadIdx.x;

    float lg[NE];
    const float* p0 = part + (size_t)tok * NE;
#pragma unroll
    for (int g = 0; g < 16; ++g) {
        f4 v = *(const f4*)(p0 + g * 4);
        lg[4 * g + 0] = v.x; lg[4 * g + 1] = v.y;
        lg[4 * g + 2] = v.z; lg[4 * g + 3] = v.w;
    }
    for (int ks = 1; ks < nks; ++ks) {
        const float* pk = part + ((size_t)ks * ntok + tok) * NE;
#pragma unroll
        for (int g = 0; g < 16; ++g) {
            f4 v = *(const f4*)(pk + g * 4);
            lg[4 * g + 0] += v.x; lg[4 * g + 1] += v.y;
            lg[4 * g + 2] += v.z; lg[4 * g + 3] += v.w;
        }
    }

    float m1 = -INFINITY, m2 = -INFINITY;
    int i1 = 0, i2 = 0;
#pragma unroll
    for (int e = 0; e < NE; ++e) {
        float v = lg[e];
        // strict > keeps lowest index on ties, matching jax.lax.top_k
        if (v > m1)      { m2 = m1; i2 = i1; m1 = v; i1 = e; }
        else if (v > m2) { m2 = v;  i2 = e; }
    }
    const float p1 = 1.0f / (1.0f + expf(m2 - m1));   // stable: m2 <= m1
    const float p2 = 1.0f - p1;

    out[(size_t)tok * 2 + 0] = (float)i1;
    out[(size_t)tok * 2 + 1] = (float)i2;
    float* vals = out + (size_t)ntok * 2;
    vals[(size_t)tok * 2 + 0] = p1;
    vals[(size_t)tok * 2 + 1] = p2;
}

extern "C" void kernel_launch(void* const* d_in, const int* in_sizes, int n_in,
                              void* d_out, int out_size, void* d_ws, size_t ws_size,
                              hipStream_t stream)
{
    const float* x = (const float*)d_in[0];
    const float* W = (const float*)d_in[1];
    float* out = (float*)d_out;
    float* Wt4 = (float*)d_ws;
    float* part = Wt4 + WT4N;

    const int ntok = in_sizes[0] / D;                  // 16384
    int KS = 8;
    while (KS > 1 &&
           ((size_t)WT4N + (size_t)KS * ntok * NE) * 4 > ws_size)
        KS >>= 1;

    wtrans<<<(D * NE) / 256, 256, 0, stream>>>(W, Wt4);
    moe_gemm_part<<<(ntok / TPB) * KS, TPB, 0, stream>>>(x, Wt4, part, ntok, KS);
    moe_top2<<<ntok / 64, 64, 0, stream>>>(part, out, ntok, KS);
}

// Round 4
// 46.284 us; speedup vs baseline: 18.7250x; 4.8853x over previous
//
#include <hip/hip_runtime.h>
#include <math.h>

typedef float f4 __attribute__((ext_vector_type(4)));
typedef float f32x4 __attribute__((ext_vector_type(4)));
typedef short bf16x8 __attribute__((ext_vector_type(8)));

#define D      2048
#define NE     64
#define TOKB   32               // tokens per block
#define KSPLIT 4                // waves per block, k-split in-block
#define KRNG   (D / KSPLIT)     // 512 k per wave
#define KCH    32               // k per chunk
#define NCH    (KRNG / KCH)     // 16 chunks
#define LROW   40               // ushorts per staged row (64B data + 16B pad)
#define SLAB   10240            // bytes per wave LDS slab

__device__ __forceinline__ unsigned short bf16rne(float f) {
    unsigned int u = __builtin_bit_cast(unsigned int, f);
    u += 0x7fffu + ((u >> 16) & 1u);
    return (unsigned short)(u >> 16);
}
__device__ __forceinline__ float bf2f(unsigned short h) {
    unsigned int u = (unsigned int)h << 16;
    return __builtin_bit_cast(float, u);
}

// ---- kernel 0: W -> (Wh, Wl) bf16 split, [e][k] layout kept ----
__global__ __launch_bounds__(256)
void wprep(const float* __restrict__ W,
           unsigned short* __restrict__ Wh,
           unsigned short* __restrict__ Wl)
{
    const int i = blockIdx.x * 256 + threadIdx.x;
    const float w = W[i];
    const unsigned short h = bf16rne(w);
    Wh[i] = h;
    Wl[i] = bf16rne(w - bf2f(h));
}

// ---- kernel 1: fused split-MFMA logits + in-block reduce + top2 + softmax ----
__global__ __launch_bounds__(256)
void moe_fused(const float* __restrict__ x,
               const unsigned short* __restrict__ Wh,
               const unsigned short* __restrict__ Wl,
               float* __restrict__ out, int ntok)
{
    __shared__ __align__(16) char smem[KSPLIT][SLAB];

    const int t    = threadIdx.x;
    const int w    = t >> 6;            // wave id = k-split id
    const int l    = t & 63;
    const int tok0 = blockIdx.x * TOKB;
    const int k0   = w * KRNG;

    unsigned short* stg = (unsigned short*)smem[w];   // wave-private

    const int srow = l >> 3;            // staging row base (0..7)
    const int sg   = l & 7;             // f4 granule within 32-k row
    const int ar   = l & 15;            // a-frag token row within 16-tile
    const int akb  = (l >> 4) * 8;      // frag k-offset (ushorts)
    const int be   = l & 15;            // b-frag expert within 16-tile

    const float* xbase = x + (size_t)tok0 * D + k0 + sg * 4;

    f4 xr0, xr1, xr2, xr3;

    // coalesced: lanes 0..7 cover one row's 32 k (128B); wave = 8 rows/pass
#define LOADX(ch) { \
    const float* p_ = xbase + (ch) * KCH; \
    xr0 = *(const f4*)(p_ + (size_t)(srow     ) * D); \
    xr1 = *(const f4*)(p_ + (size_t)(srow +  8) * D); \
    xr2 = *(const f4*)(p_ + (size_t)(srow + 16) * D); \
    xr3 = *(const f4*)(p_ + (size_t)(srow + 24) * D); }

#define CVT1(v, buf, row) { \
    unsigned short h0_=bf16rne(v.x), h1_=bf16rne(v.y), h2_=bf16rne(v.z), h3_=bf16rne(v.w); \
    unsigned short l0_=bf16rne(v.x-bf2f(h0_)), l1_=bf16rne(v.y-bf2f(h1_)); \
    unsigned short l2_=bf16rne(v.z-bf2f(h2_)), l3_=bf16rne(v.w-bf2f(h3_)); \
    uint2 hw_, lw_; \
    hw_.x=(unsigned)h0_|((unsigned)h1_<<16); hw_.y=(unsigned)h2_|((unsigned)h3_<<16); \
    lw_.x=(unsigned)l0_|((unsigned)l1_<<16); lw_.y=(unsigned)l2_|((unsigned)l3_<<16); \
    *(uint2*)&stg[(((buf)*2 + 0)*TOKB + (row))*LROW + sg*4] = hw_; \
    *(uint2*)&stg[(((buf)*2 + 1)*TOKB + (row))*LROW + sg*4] = lw_; }

#define CVTWR(buf) { CVT1(xr0, buf, srow); CVT1(xr1, buf, srow+8); \
                     CVT1(xr2, buf, srow+16); CVT1(xr3, buf, srow+24); }

    const f32x4 zz = {0.f, 0.f, 0.f, 0.f};
    f32x4 acc[2][4];
#pragma unroll
    for (int i = 0; i < 2; ++i)
#pragma unroll
        for (int j = 0; j < 4; ++j) acc[i][j] = zz;

    LOADX(0);
    CVTWR(0);

    for (int ch = 0; ch < NCH; ++ch) {
        // B-frags from L2-resident Wh/Wl (lane: expert et*16+be, 8 k at akb)
        bf16x8 bh[4], bl[4];
        const size_t kk = (size_t)(k0 + ch * KCH + akb);
#pragma unroll
        for (int et = 0; et < 4; ++et) {
            const size_t off = (size_t)(et * 16 + be) * D + kk;
            bh[et] = *(const bf16x8*)(Wh + off);
            bl[et] = *(const bf16x8*)(Wl + off);
        }
        // issue next chunk's HBM loads early
        if (ch + 1 < NCH) LOADX(ch + 1);

        // A-frags from wave-private LDS (pad-40 rows: conflict-light)
        bf16x8 ah[2], al[2];
        const int buf = ch & 1;
#pragma unroll
        for (int rt = 0; rt < 2; ++rt) {
            const int row = rt * 16 + ar;
            ah[rt] = *(const bf16x8*)&stg[((buf*2 + 0)*TOKB + row)*LROW + akb];
            al[rt] = *(const bf16x8*)&stg[((buf*2 + 1)*TOKB + row)*LROW + akb];
        }

        // 3-term split product: xh*wh + xh*wl + xl*wh
#pragma unroll
        for (int rt = 0; rt < 2; ++rt)
#pragma unroll
            for (int et = 0; et < 4; ++et) {
                acc[rt][et] = __builtin_amdgcn_mfma_f32_16x16x32_bf16(ah[rt], bh[et], acc[rt][et], 0, 0, 0);
                acc[rt][et] = __builtin_amdgcn_mfma_f32_16x16x32_bf16(ah[rt], bl[et], acc[rt][et], 0, 0, 0);
                acc[rt][et] = __builtin_amdgcn_mfma_f32_16x16x32_bf16(al[rt], bh[et], acc[rt][et], 0, 0, 0);
            }

        // convert + write next chunk into other buffer (wave-private: no barrier)
        if (ch + 1 < NCH) CVTWR((ch + 1) & 1);
    }

#undef LOADX
#undef CVT1
#undef CVTWR

    // ---- epilogue: per-wave partials -> LDS (alias dead staging slab) ----
    float* cred = (float*)smem[w];                 // [32][68] f32 = 8704 B
#pragma unroll
    for (int rt = 0; rt < 2; ++rt)
#pragma unroll
        for (int et = 0; et < 4; ++et)
#pragma unroll
            for (int r = 0; r < 4; ++r) {
                const int tokl = rt * 16 + (l >> 4) * 4 + r;   // D row = token
                cred[tokl * 68 + et * 16 + (l & 15)] = acc[rt][et][r];
            }
    __syncthreads();

    // ---- reduce 4 k-splits + top-2 + softmax ----
    {
        const int tokl = t >> 3;        // 0..31
        const int eg   = t & 7;         // expert octet
        f4 s0 = {0.f,0.f,0.f,0.f}, s1 = {0.f,0.f,0.f,0.f};
#pragma unroll
        for (int ww = 0; ww < 4; ++ww) {
            const float* cw = (const float*)smem[ww] + tokl * 68 + eg * 8;
            s0 += *(const f4*)cw;
            s1 += *(const f4*)(cw + 4);
        }
        const float vv[8] = {s0.x, s0.y, s0.z, s0.w, s1.x, s1.y, s1.z, s1.w};
        float m1 = -INFINITY, m2 = -INFINITY;
        int i1 = 0, i2 = 0;
#pragma unroll
        for (int j = 0; j < 8; ++j) {           // ids ascending: strict > = lowest-index tie-break
            const float v = vv[j];
            const int id = eg * 8 + j;
            if (v > m1)      { m2 = m1; i2 = i1; m1 = v; i1 = id; }
            else if (v > m2) { m2 = v;  i2 = id; }
        }
        // butterfly merge across the 8-lane expert-octet group
#pragma unroll
        for (int m = 1; m < 8; m <<= 1) {
            const float om1 = __shfl_xor(m1, m);
            const int   oi1 = __shfl_xor(i1, m);
            const float om2 = __shfl_xor(m2, m);
            const int   oi2 = __shfl_xor(i2, m);
            const bool b1 = (om1 > m1) || (om1 == m1 && oi1 < i1);
            const float c2v = b1 ? m1 : om1;  const int c2i = b1 ? i1 : oi1;
            const float c3v = b1 ? om2 : m2;  const int c3i = b1 ? oi2 : i2;
            if (b1) { m1 = om1; i1 = oi1; }
            const bool b2 = (c3v > c2v) || (c3v == c2v && c3i < c2i);
            m2 = b2 ? c3v : c2v;  i2 = b2 ? c3i : c2i;
        }
        if (eg == 0) {
            const int tok = tok0 + tokl;
            out[(size_t)tok * 2 + 0] = (float)i1;
            out[(size_t)tok * 2 + 1] = (float)i2;
            const float p1 = 1.0f / (1.0f + expf(m2 - m1));   // stable: m2 <= m1
            float* vals = out + (size_t)ntok * 2;
            vals[(size_t)tok * 2 + 0] = p1;
            vals[(size_t)tok * 2 + 1] = 1.0f - p1;
        }
    }
}

extern "C" void kernel_launch(void* const* d_in, const int* in_sizes, int n_in,
                              void* d_out, int out_size, void* d_ws, size_t ws_size,
                              hipStream_t stream)
{
    const float* x = (const float*)d_in[0];
    const float* W = (const float*)d_in[1];
    float* out = (float*)d_out;
    unsigned short* Wh = (unsigned short*)d_ws;
    unsigned short* Wl = Wh + (size_t)NE * D;

    const int ntok = in_sizes[0] / D;                 // 16384
    wprep<<<(NE * D) / 256, 256, 0, stream>>>(W, Wh, Wl);
    moe_fused<<<ntok / TOKB, 256, 0, stream>>>(x, Wh, Wl, out, ntok);
}